// Round 2
// baseline (775.755 us; speedup 1.0000x reference)
//
#include <hip/hip_runtime.h>
#include <stdint.h>

#define NB   128
#define HH   512
#define WW   512
#define IMG  (HH*WW)          // 262144 px per image
#define NPIX (NB*IMG)         // 33,554,432 px total
#define NBINS 256
#define CLIPLIM 80            // int(5.0 * 4096 / 256)
#define LUT_SCALE (255.0f/4096.0f)

// NumPy 2 promotes int32 * python-float -> float64, so the np reference's
// gray channel is computed (and rounded, half-even) in double. Match it.
__device__ __forceinline__ int gray_of(float bc, float gc, float rc) {
    bc = fminf(fmaxf(bc, 0.0f), 255.0f);
    gc = fminf(fmaxf(gc, 0.0f), 255.0f);
    rc = fminf(fmaxf(rc, 0.0f), 255.0f);
    double bi = (double)(int)bc;
    double gi = (double)(int)gc;
    double ri = (double)(int)rc;
    double s = 0.114 * bi + 0.587 * gi + 0.299 * ri;
    int v = (int)rint(s);                   // round half-to-even in f64, like np.round
    v = v < 0 ? 0 : (v > 255 ? 255 : v);
    return v;
}

// One block per 64x64 tile: stream tile, emit gray u8, LDS histogram,
// then fused clip/redistribute/exact-scan/LUT.
template <bool WRITE_GRAY>
__global__ __launch_bounds__(256) void k_hist_lut(const float* __restrict__ in,
                                                  uint8_t* __restrict__ gray,
                                                  uint8_t* __restrict__ lut) {
    __shared__ int   hist[NBINS];
    __shared__ float sc[NBINS];
    __shared__ int   excess_s;
    const int t   = threadIdx.x;
    const int blk = blockIdx.x;             // b*64 + ty*8 + tx
    const int b   = blk >> 6;
    const int ty  = (blk >> 3) & 7;
    const int tx  = blk & 7;
    const int y0  = ty * 64, x0 = tx * 64;

    hist[t] = 0;
    if (t == 0) excess_s = 0;
    __syncthreads();

    const int rwi = t >> 4;                 // row within a 16-row group
    const int c   = (t & 15) * 4;           // 4-px column group
    #pragma unroll
    for (int it = 0; it < 4; ++it) {
        const int y = y0 + it * 16 + rwi;
        const size_t pbase = ((size_t)b * IMG + (size_t)y * WW + (x0 + c));
        const float4* p = (const float4*)(in + pbase * 3);
        float4 a0 = p[0], a1 = p[1], a2 = p[2];
        int v0 = gray_of(a0.x, a0.y, a0.z);
        int v1 = gray_of(a0.w, a1.x, a1.y);
        int v2 = gray_of(a1.z, a1.w, a2.x);
        int v3 = gray_of(a2.y, a2.z, a2.w);
        atomicAdd(&hist[v0], 1);
        atomicAdd(&hist[v1], 1);
        atomicAdd(&hist[v2], 1);
        atomicAdd(&hist[v3], 1);
        if (WRITE_GRAY)
            *(uchar4*)(gray + pbase) = make_uchar4((uint8_t)v0, (uint8_t)v1,
                                                   (uint8_t)v2, (uint8_t)v3);
    }
    __syncthreads();

    const int h = hist[t];
    atomicAdd(&excess_s, h > CLIPLIM ? h - CLIPLIM : 0);
    __syncthreads();
    const float e  = (float)excess_s * (1.0f / 256.0f);          // exact
    const float hc = (float)(h < CLIPLIM ? h : CLIPLIM) + e;     // exact (k/256)

    // inclusive scan; every partial sum is k/256 with k < 2^20 -> exact in fp32,
    // so parallel reassociation == sequential cumsum bit-for-bit.
    sc[t] = hc;
    __syncthreads();
    #pragma unroll
    for (int off = 1; off < NBINS; off <<= 1) {
        float add = (t >= off) ? sc[t - off] : 0.0f;
        __syncthreads();
        sc[t] += add;
        __syncthreads();
    }
    float l = rintf(__fmul_rn(sc[t], LUT_SCALE));   // np ref: f32 array * weak scalar -> f32
    l = fminf(fmaxf(l, 0.0f), 255.0f);
    lut[blk * NBINS + t] = (uint8_t)l;
}

__device__ __forceinline__ float4 bilerp_group(const uint8_t* __restrict__ lut,
                                               int b, int y, int x,
                                               const int vv[4]) {
    const int   y1  = (y - 32) >> 6;                       // floor(y/64 - .5)
    const float ya  = (float)((y + 32) & 63) * (1.0f/64.0f);
    const int   y1i = y1 < 0 ? 0 : y1;
    const int   y2i = (y1 + 1) > 7 ? 7 : (y1 + 1);
    const uint8_t* lb  = lut + b * (64 * NBINS);
    const uint8_t* lr1 = lb + y1i * (8 * NBINS);
    const uint8_t* lr2 = lb + y2i * (8 * NBINS);
    const float iya = __fsub_rn(1.0f, ya);

    float res[4];
    #pragma unroll
    for (int j = 0; j < 4; ++j) {
        const int xx  = x + j;
        const int x1  = (xx - 32) >> 6;
        const float xa  = (float)((xx + 32) & 63) * (1.0f/64.0f);
        const int  x1i = x1 < 0 ? 0 : x1;
        const int  x2i = (x1 + 1) > 7 ? 7 : (x1 + 1);
        const int  v   = vv[j];
        const float r11 = (float)lr1[x1i * NBINS + v];
        const float r12 = (float)lr1[x2i * NBINS + v];
        const float r21 = (float)lr2[x1i * NBINS + v];
        const float r22 = (float)lr2[x2i * NBINS + v];
        const float ixa = __fsub_rn(1.0f, xa);
        const float top = __fadd_rn(__fmul_rn(r11, ixa), __fmul_rn(r12, xa));
        const float bot = __fadd_rn(__fmul_rn(r21, ixa), __fmul_rn(r22, xa));
        float r = __fadd_rn(__fmul_rn(top, iya), __fmul_rn(bot, ya));
        r = rintf(r);
        res[j] = fminf(fmaxf(r, 0.0f), 255.0f);
    }
    return make_float4(res[0], res[1], res[2], res[3]);
}

__device__ __forceinline__ void store_group(float* __restrict__ out, int pix, float4 r) {
    float4* o = (float4*)(out + (size_t)pix * 3);
    o[0] = make_float4(r.x, r.x, r.x, r.y);
    o[1] = make_float4(r.y, r.y, r.z, r.z);
    o[2] = make_float4(r.z, r.w, r.w, r.w);
}

// Grid-stride apply: 4 px/thread, bilinear over tile LUTs, 3-channel fp32 out.
__global__ __launch_bounds__(256) void k_apply(const uint8_t* __restrict__ gray,
                                               const uint8_t* __restrict__ lut,
                                               float* __restrict__ out) {
    const int nG = NPIX / 4;
    for (int g = blockIdx.x * blockDim.x + threadIdx.x; g < nG;
         g += gridDim.x * blockDim.x) {
        const int pix = g << 2;
        const int b   = pix >> 18;
        const int rem = pix & (IMG - 1);
        const int y   = rem >> 9;
        const int x   = rem & (WW - 1);
        const uchar4 v4 = ((const uchar4*)gray)[g];
        const int vv[4] = {v4.x, v4.y, v4.z, v4.w};
        store_group(out, pix, bilerp_group(lut, b, y, x, vv));
    }
}

// Fallback when ws can't hold the gray buffer: recompute gray from input.
__global__ __launch_bounds__(256) void k_apply_recompute(const float* __restrict__ in,
                                                         const uint8_t* __restrict__ lut,
                                                         float* __restrict__ out) {
    const int nG = NPIX / 4;
    for (int g = blockIdx.x * blockDim.x + threadIdx.x; g < nG;
         g += gridDim.x * blockDim.x) {
        const int pix = g << 2;
        const int b   = pix >> 18;
        const int rem = pix & (IMG - 1);
        const int y   = rem >> 9;
        const int x   = rem & (WW - 1);
        const float4* p = (const float4*)(in + (size_t)pix * 3);
        float4 a0 = p[0], a1 = p[1], a2 = p[2];
        const int vv[4] = {gray_of(a0.x, a0.y, a0.z), gray_of(a0.w, a1.x, a1.y),
                           gray_of(a1.z, a1.w, a2.x), gray_of(a2.y, a2.z, a2.w)};
        store_group(out, pix, bilerp_group(lut, b, y, x, vv));
    }
}

extern "C" void kernel_launch(void* const* d_in, const int* in_sizes, int n_in,
                              void* d_out, int out_size, void* d_ws, size_t ws_size,
                              hipStream_t stream) {
    const float* in  = (const float*)d_in[0];
    float*       out = (float*)d_out;
    const size_t lut_bytes  = (size_t)NB * 64 * NBINS;   // 2 MB
    const size_t gray_bytes = (size_t)NPIX;              // 33.5 MB

    if (ws_size >= gray_bytes + lut_bytes) {
        uint8_t* gray = (uint8_t*)d_ws;
        uint8_t* lut  = (uint8_t*)d_ws + gray_bytes;
        k_hist_lut<true><<<NB * 64, 256, 0, stream>>>(in, gray, lut);
        k_apply<<<8192, 256, 0, stream>>>(gray, lut, out);
    } else {
        uint8_t* lut = (uint8_t*)d_ws;
        k_hist_lut<false><<<NB * 64, 256, 0, stream>>>(in, nullptr, lut);
        k_apply_recompute<<<8192, 256, 0, stream>>>(in, lut, out);
    }
}

// Round 5
// 704.240 us; speedup vs baseline: 1.1015x; 1.1015x over previous
//
#include <hip/hip_runtime.h>
#include <stdint.h>

#define NB   128
#define HH   512
#define WW   512
#define IMG  (HH*WW)          // 262144 px per image
#define NPIX (NB*IMG)         // 33,554,432 px total
#define NBINS 256
#define CLIPLIM 80            // int(5.0 * 4096 / 256)
#define LUT_SCALE (255.0f/4096.0f)

// NumPy 2 promotes int32 * python-float -> float64, so the np reference's
// gray channel is computed (and rounded, half-even) in double. Match it.
__device__ __forceinline__ int gray_of(float bc, float gc, float rc) {
    bc = fminf(fmaxf(bc, 0.0f), 255.0f);
    gc = fminf(fmaxf(gc, 0.0f), 255.0f);
    rc = fminf(fmaxf(rc, 0.0f), 255.0f);
    double bi = (double)(int)bc;
    double gi = (double)(int)gc;
    double ri = (double)(int)rc;
    double s = 0.114 * bi + 0.587 * gi + 0.299 * ri;
    int v = (int)rint(s);                   // round half-to-even in f64, like np.round
    v = v < 0 ? 0 : (v > 255 ? 255 : v);
    return v;
}

// One block per 64x64 tile: stream tile, emit gray u8, LDS histogram,
// then fused clip/redistribute/exact-scan/LUT.  (unchanged, validated round 2)
template <bool WRITE_GRAY>
__global__ __launch_bounds__(256) void k_hist_lut(const float* __restrict__ in,
                                                  uint8_t* __restrict__ gray,
                                                  uint8_t* __restrict__ lut) {
    __shared__ int   hist[NBINS];
    __shared__ float sc[NBINS];
    __shared__ int   excess_s;
    const int t   = threadIdx.x;
    const int blk = blockIdx.x;             // b*64 + ty*8 + tx
    const int b   = blk >> 6;
    const int ty  = (blk >> 3) & 7;
    const int tx  = blk & 7;
    const int y0  = ty * 64, x0 = tx * 64;

    hist[t] = 0;
    if (t == 0) excess_s = 0;
    __syncthreads();

    const int rwi = t >> 4;                 // row within a 16-row group
    const int c   = (t & 15) * 4;           // 4-px column group
    #pragma unroll
    for (int it = 0; it < 4; ++it) {
        const int y = y0 + it * 16 + rwi;
        const size_t pbase = ((size_t)b * IMG + (size_t)y * WW + (x0 + c));
        const float4* p = (const float4*)(in + pbase * 3);
        float4 a0 = p[0], a1 = p[1], a2 = p[2];
        int v0 = gray_of(a0.x, a0.y, a0.z);
        int v1 = gray_of(a0.w, a1.x, a1.y);
        int v2 = gray_of(a1.z, a1.w, a2.x);
        int v3 = gray_of(a2.y, a2.z, a2.w);
        atomicAdd(&hist[v0], 1);
        atomicAdd(&hist[v1], 1);
        atomicAdd(&hist[v2], 1);
        atomicAdd(&hist[v3], 1);
        if (WRITE_GRAY)
            *(uchar4*)(gray + pbase) = make_uchar4((uint8_t)v0, (uint8_t)v1,
                                                   (uint8_t)v2, (uint8_t)v3);
    }
    __syncthreads();

    const int h = hist[t];
    atomicAdd(&excess_s, h > CLIPLIM ? h - CLIPLIM : 0);
    __syncthreads();
    const float e  = (float)excess_s * (1.0f / 256.0f);          // exact
    const float hc = (float)(h < CLIPLIM ? h : CLIPLIM) + e;     // exact (k/256)

    // inclusive scan; every partial sum is k/256 with k < 2^20 -> exact in fp32
    sc[t] = hc;
    __syncthreads();
    #pragma unroll
    for (int off = 1; off < NBINS; off <<= 1) {
        float add = (t >= off) ? sc[t - off] : 0.0f;
        __syncthreads();
        sc[t] += add;
        __syncthreads();
    }
    float l = rintf(__fmul_rn(sc[t], LUT_SCALE));   // f32 array * weak scalar -> f32
    l = fminf(fmaxf(l, 0.0f), 255.0f);
    lut[blk * NBINS + t] = (uint8_t)l;
}

// Apply v2: one block = 1024 px = exactly 2 rows of one image.
// LUT rows staged in LDS (gathers -> LDS); output staged in stride-13 LDS
// so global stores are perfectly dense float4 per instruction.
__global__ __launch_bounds__(256) void k_apply2(const uint8_t* __restrict__ gray,
                                                const uint8_t* __restrict__ lut,
                                                float* __restrict__ out) {
    __shared__ uint8_t lut_s[4][2048];      // [row0:lr1,lr2, row1:lr1,lr2]
    __shared__ float   outs[256 * 13];      // stride-13 padded (bank-conflict-free)

    const int t   = threadIdx.x;
    const int idx = blockIdx.x;             // 0..32767
    const int b   = idx >> 8;
    const int y0  = (idx & 255) << 1;       // first of 2 rows

    // per-row LUT bases + y-weights
    float ya_r[2];
    const uint8_t* src[4];
    #pragma unroll
    for (int r = 0; r < 2; ++r) {
        const int y   = y0 + r;
        const int y1  = (y - 32) >> 6;
        const int y1i = y1 < 0 ? 0 : y1;
        const int y2i = (y1 + 1) > 7 ? 7 : (y1 + 1);
        ya_r[r] = (float)((y + 32) & 63) * (1.0f / 64.0f);
        src[2*r]   = lut + ((b << 6) + (y1i << 3)) * 256;
        src[2*r+1] = lut + ((b << 6) + (y2i << 3)) * 256;
    }

    // stage 4 x 2KB LUT rows into LDS, coalesced 32 B/thread
    {
        const int r   = t >> 6;
        const int off = (t & 63) * 32;
        const uint4* s = (const uint4*)(src[r] + off);
        uint4 a = s[0], c2 = s[1];
        *(uint4*)(&lut_s[r][off])      = a;
        *(uint4*)(&lut_s[r][off + 16]) = c2;
    }
    __syncthreads();

    // each thread: 4 px of row h at x..x+3
    const int h  = t >> 7;
    const int xb = (t & 127) << 2;
    const float ya  = ya_r[h];
    const float iya = __fsub_rn(1.0f, ya);
    const uint8_t* l1 = lut_s[2*h];
    const uint8_t* l2 = lut_s[2*h + 1];

    const uchar4 v4 = ((const uchar4*)gray)[idx * 256 + t];
    const int vv[4] = {v4.x, v4.y, v4.z, v4.w};

    #pragma unroll
    for (int j = 0; j < 4; ++j) {
        const int xx  = xb + j;
        const int x1  = (xx - 32) >> 6;
        const float xa  = (float)((xx + 32) & 63) * (1.0f/64.0f);
        const int  x1i = x1 < 0 ? 0 : x1;
        const int  x2i = (x1 + 1) > 7 ? 7 : (x1 + 1);
        const int  v   = vv[j];
        const float r11 = (float)l1[(x1i << 8) + v];
        const float r12 = (float)l1[(x2i << 8) + v];
        const float r21 = (float)l2[(x1i << 8) + v];
        const float r22 = (float)l2[(x2i << 8) + v];
        const float ixa = __fsub_rn(1.0f, xa);
        const float top = __fadd_rn(__fmul_rn(r11, ixa), __fmul_rn(r12, xa));
        const float bot = __fadd_rn(__fmul_rn(r21, ixa), __fmul_rn(r22, xa));
        float r = rintf(__fadd_rn(__fmul_rn(top, iya), __fmul_rn(bot, ya)));
        r = fminf(fmaxf(r, 0.0f), 255.0f);
        // px j -> logical floats 12t+3j .. 12t+3j+2, stored at slot 13t
        outs[t * 13 + 3*j + 0] = r;
        outs[t * 13 + 3*j + 1] = r;
        outs[t * 13 + 3*j + 2] = r;
    }
    __syncthreads();

    // dense stores: f4 #k (k = t + 256*i) = logical floats 4k..4k+3,
    // which always lie inside one 12-float slot (4k mod 12 in {0,4,8}).
    float4* og = (float4*)out + (size_t)idx * 768;
    #pragma unroll
    for (int i = 0; i < 3; ++i) {
        const int k    = t + (i << 8);
        const int slot = k / 3;
        const int c    = (k - slot * 3) * 4;
        const float* p = &outs[slot * 13 + c];
        og[k] = make_float4(p[0], p[1], p[2], p[3]);
    }
}

// ---- fallback path (ws too small): original global-LUT bilerp ----
__device__ __forceinline__ float4 bilerp_group(const uint8_t* __restrict__ lut,
                                               int b, int y, int x,
                                               const int vv[4]) {
    const int   y1  = (y - 32) >> 6;
    const float ya  = (float)((y + 32) & 63) * (1.0f/64.0f);
    const int   y1i = y1 < 0 ? 0 : y1;
    const int   y2i = (y1 + 1) > 7 ? 7 : (y1 + 1);
    const uint8_t* lb  = lut + b * (64 * NBINS);
    const uint8_t* lr1 = lb + y1i * (8 * NBINS);
    const uint8_t* lr2 = lb + y2i * (8 * NBINS);
    const float iya = __fsub_rn(1.0f, ya);
    float res[4];
    #pragma unroll
    for (int j = 0; j < 4; ++j) {
        const int xx  = x + j;
        const int x1  = (xx - 32) >> 6;
        const float xa  = (float)((xx + 32) & 63) * (1.0f/64.0f);
        const int  x1i = x1 < 0 ? 0 : x1;
        const int  x2i = (x1 + 1) > 7 ? 7 : (x1 + 1);
        const int  v   = vv[j];
        const float r11 = (float)lr1[x1i * NBINS + v];
        const float r12 = (float)lr1[x2i * NBINS + v];
        const float r21 = (float)lr2[x1i * NBINS + v];
        const float r22 = (float)lr2[x2i * NBINS + v];
        const float ixa = __fsub_rn(1.0f, xa);
        const float top = __fadd_rn(__fmul_rn(r11, ixa), __fmul_rn(r12, xa));
        const float bot = __fadd_rn(__fmul_rn(r21, ixa), __fmul_rn(r22, xa));
        float r = __fadd_rn(__fmul_rn(top, iya), __fmul_rn(bot, ya));
        r = rintf(r);
        res[j] = fminf(fmaxf(r, 0.0f), 255.0f);
    }
    return make_float4(res[0], res[1], res[2], res[3]);
}

__global__ __launch_bounds__(256) void k_apply_recompute(const float* __restrict__ in,
                                                         const uint8_t* __restrict__ lut,
                                                         float* __restrict__ out) {
    const int nG = NPIX / 4;
    for (int g = blockIdx.x * blockDim.x + threadIdx.x; g < nG;
         g += gridDim.x * blockDim.x) {
        const int pix = g << 2;
        const int b   = pix >> 18;
        const int rem = pix & (IMG - 1);
        const int y   = rem >> 9;
        const int x   = rem & (WW - 1);
        const float4* p = (const float4*)(in + (size_t)pix * 3);
        float4 a0 = p[0], a1 = p[1], a2 = p[2];
        const int vv[4] = {gray_of(a0.x, a0.y, a0.z), gray_of(a0.w, a1.x, a1.y),
                           gray_of(a1.z, a1.w, a2.x), gray_of(a2.y, a2.z, a2.w)};
        float4 r = bilerp_group(lut, b, y, x, vv);
        float4* o = (float4*)(out + (size_t)pix * 3);
        o[0] = make_float4(r.x, r.x, r.x, r.y);
        o[1] = make_float4(r.y, r.y, r.z, r.z);
        o[2] = make_float4(r.z, r.w, r.w, r.w);
    }
}

extern "C" void kernel_launch(void* const* d_in, const int* in_sizes, int n_in,
                              void* d_out, int out_size, void* d_ws, size_t ws_size,
                              hipStream_t stream) {
    const float* in  = (const float*)d_in[0];
    float*       out = (float*)d_out;
    const size_t lut_bytes  = (size_t)NB * 64 * NBINS;   // 2 MB
    const size_t gray_bytes = (size_t)NPIX;              // 33.5 MB

    if (ws_size >= gray_bytes + lut_bytes) {
        uint8_t* gray = (uint8_t*)d_ws;
        uint8_t* lut  = (uint8_t*)d_ws + gray_bytes;
        k_hist_lut<true><<<NB * 64, 256, 0, stream>>>(in, gray, lut);
        k_apply2<<<NPIX / 1024, 256, 0, stream>>>(gray, lut, out);
    } else {
        uint8_t* lut = (uint8_t*)d_ws;
        k_hist_lut<false><<<NB * 64, 256, 0, stream>>>(in, nullptr, lut);
        k_apply_recompute<<<8192, 256, 0, stream>>>(in, lut, out);
    }
}

// Round 6
// 701.963 us; speedup vs baseline: 1.1051x; 1.0032x over previous
//
#include <hip/hip_runtime.h>
#include <stdint.h>

#define NB   128
#define HH   512
#define WW   512
#define IMG  (HH*WW)          // 262144 px per image
#define NPIX (NB*IMG)         // 33,554,432 px total
#define NBINS 256
#define CLIPLIM 80            // int(5.0 * 4096 / 256)
#define LUT_SCALE (255.0f/4096.0f)

// NumPy 2 promotes int32 * python-float -> float64, so the np reference's
// gray channel is computed (and rounded, half-even) in double. Match it.
__device__ __forceinline__ int gray_of(float bc, float gc, float rc) {
    bc = fminf(fmaxf(bc, 0.0f), 255.0f);
    gc = fminf(fmaxf(gc, 0.0f), 255.0f);
    rc = fminf(fmaxf(rc, 0.0f), 255.0f);
    double bi = (double)(int)bc;
    double gi = (double)(int)gc;
    double ri = (double)(int)rc;
    double s = 0.114 * bi + 0.587 * gi + 0.299 * ri;
    int v = (int)rint(s);                   // round half-to-even in f64, like np.round
    v = v < 0 ? 0 : (v > 255 ? 255 : v);
    return v;
}

// One block per 64x64 tile: stream tile, emit gray u8, LDS histogram,
// then fused clip/redistribute/exact-scan/LUT.
// Round-6 change: excess reduction via per-wave shuffle butterfly + 1 atomic
// per wave (was: 256 atomicAdds to ONE LDS address = 64-way serialized/wave).
template <bool WRITE_GRAY>
__global__ __launch_bounds__(256) void k_hist_lut(const float* __restrict__ in,
                                                  uint8_t* __restrict__ gray,
                                                  uint8_t* __restrict__ lut) {
    __shared__ int   hist[NBINS];
    __shared__ float sc[NBINS];
    __shared__ int   excess_s;
    const int t   = threadIdx.x;
    const int blk = blockIdx.x;             // b*64 + ty*8 + tx
    const int b   = blk >> 6;
    const int ty  = (blk >> 3) & 7;
    const int tx  = blk & 7;
    const int y0  = ty * 64, x0 = tx * 64;

    hist[t] = 0;
    if (t == 0) excess_s = 0;
    __syncthreads();

    const int rwi = t >> 4;                 // row within a 16-row group
    const int c   = (t & 15) * 4;           // 4-px column group
    #pragma unroll
    for (int it = 0; it < 4; ++it) {
        const int y = y0 + it * 16 + rwi;
        const size_t pbase = ((size_t)b * IMG + (size_t)y * WW + (x0 + c));
        const float4* p = (const float4*)(in + pbase * 3);
        float4 a0 = p[0], a1 = p[1], a2 = p[2];
        int v0 = gray_of(a0.x, a0.y, a0.z);
        int v1 = gray_of(a0.w, a1.x, a1.y);
        int v2 = gray_of(a1.z, a1.w, a2.x);
        int v3 = gray_of(a2.y, a2.z, a2.w);
        atomicAdd(&hist[v0], 1);
        atomicAdd(&hist[v1], 1);
        atomicAdd(&hist[v2], 1);
        atomicAdd(&hist[v3], 1);
        if (WRITE_GRAY)
            *(uchar4*)(gray + pbase) = make_uchar4((uint8_t)v0, (uint8_t)v1,
                                                   (uint8_t)v2, (uint8_t)v3);
    }
    __syncthreads();

    const int h = hist[t];
    // per-wave butterfly reduction of the clip excess (integer, exact,
    // order-independent), then one LDS atomic per wave instead of 256
    // same-address atomics.
    {
        int ex = h > CLIPLIM ? h - CLIPLIM : 0;
        #pragma unroll
        for (int off = 32; off > 0; off >>= 1)
            ex += __shfl_xor(ex, off, 64);
        if ((t & 63) == 0) atomicAdd(&excess_s, ex);
    }
    __syncthreads();
    const float e  = (float)excess_s * (1.0f / 256.0f);          // exact
    const float hc = (float)(h < CLIPLIM ? h : CLIPLIM) + e;     // exact (k/256)

    // inclusive scan; every partial sum is k/256 with k < 2^20 -> exact in fp32
    sc[t] = hc;
    __syncthreads();
    #pragma unroll
    for (int off = 1; off < NBINS; off <<= 1) {
        float add = (t >= off) ? sc[t - off] : 0.0f;
        __syncthreads();
        sc[t] += add;
        __syncthreads();
    }
    float l = rintf(__fmul_rn(sc[t], LUT_SCALE));   // f32 array * weak scalar -> f32
    l = fminf(fmaxf(l, 0.0f), 255.0f);
    lut[blk * NBINS + t] = (uint8_t)l;
}

// Apply v2 (validated round 5): one block = 1024 px = exactly 2 rows of one
// image. LUT rows staged in LDS; output staged in stride-13 LDS so global
// stores are perfectly dense float4 per instruction.  UNCHANGED.
__global__ __launch_bounds__(256) void k_apply2(const uint8_t* __restrict__ gray,
                                                const uint8_t* __restrict__ lut,
                                                float* __restrict__ out) {
    __shared__ uint8_t lut_s[4][2048];      // [row0:lr1,lr2, row1:lr1,lr2]
    __shared__ float   outs[256 * 13];      // stride-13 padded (bank-conflict-free)

    const int t   = threadIdx.x;
    const int idx = blockIdx.x;             // 0..32767
    const int b   = idx >> 8;
    const int y0  = (idx & 255) << 1;       // first of 2 rows

    // per-row LUT bases + y-weights
    float ya_r[2];
    const uint8_t* src[4];
    #pragma unroll
    for (int r = 0; r < 2; ++r) {
        const int y   = y0 + r;
        const int y1  = (y - 32) >> 6;
        const int y1i = y1 < 0 ? 0 : y1;
        const int y2i = (y1 + 1) > 7 ? 7 : (y1 + 1);
        ya_r[r] = (float)((y + 32) & 63) * (1.0f / 64.0f);
        src[2*r]   = lut + ((b << 6) + (y1i << 3)) * 256;
        src[2*r+1] = lut + ((b << 6) + (y2i << 3)) * 256;
    }

    // stage 4 x 2KB LUT rows into LDS, coalesced 32 B/thread
    {
        const int r   = t >> 6;
        const int off = (t & 63) * 32;
        const uint4* s = (const uint4*)(src[r] + off);
        uint4 a = s[0], c2 = s[1];
        *(uint4*)(&lut_s[r][off])      = a;
        *(uint4*)(&lut_s[r][off + 16]) = c2;
    }
    __syncthreads();

    // each thread: 4 px of row h at x..x+3
    const int h  = t >> 7;
    const int xb = (t & 127) << 2;
    const float ya  = ya_r[h];
    const float iya = __fsub_rn(1.0f, ya);
    const uint8_t* l1 = lut_s[2*h];
    const uint8_t* l2 = lut_s[2*h + 1];

    const uchar4 v4 = ((const uchar4*)gray)[idx * 256 + t];
    const int vv[4] = {v4.x, v4.y, v4.z, v4.w};

    #pragma unroll
    for (int j = 0; j < 4; ++j) {
        const int xx  = xb + j;
        const int x1  = (xx - 32) >> 6;
        const float xa  = (float)((xx + 32) & 63) * (1.0f/64.0f);
        const int  x1i = x1 < 0 ? 0 : x1;
        const int  x2i = (x1 + 1) > 7 ? 7 : (x1 + 1);
        const int  v   = vv[j];
        const float r11 = (float)l1[(x1i << 8) + v];
        const float r12 = (float)l1[(x2i << 8) + v];
        const float r21 = (float)l2[(x1i << 8) + v];
        const float r22 = (float)l2[(x2i << 8) + v];
        const float ixa = __fsub_rn(1.0f, xa);
        const float top = __fadd_rn(__fmul_rn(r11, ixa), __fmul_rn(r12, xa));
        const float bot = __fadd_rn(__fmul_rn(r21, ixa), __fmul_rn(r22, xa));
        float r = rintf(__fadd_rn(__fmul_rn(top, iya), __fmul_rn(bot, ya)));
        r = fminf(fmaxf(r, 0.0f), 255.0f);
        // px j -> logical floats 12t+3j .. 12t+3j+2, stored at slot 13t
        outs[t * 13 + 3*j + 0] = r;
        outs[t * 13 + 3*j + 1] = r;
        outs[t * 13 + 3*j + 2] = r;
    }
    __syncthreads();

    // dense stores: f4 #k (k = t + 256*i) = logical floats 4k..4k+3,
    // which always lie inside one 12-float slot (4k mod 12 in {0,4,8}).
    float4* og = (float4*)out + (size_t)idx * 768;
    #pragma unroll
    for (int i = 0; i < 3; ++i) {
        const int k    = t + (i << 8);
        const int slot = k / 3;
        const int c    = (k - slot * 3) * 4;
        const float* p = &outs[slot * 13 + c];
        og[k] = make_float4(p[0], p[1], p[2], p[3]);
    }
}

// ---- fallback path (ws too small): original global-LUT bilerp ----
__device__ __forceinline__ float4 bilerp_group(const uint8_t* __restrict__ lut,
                                               int b, int y, int x,
                                               const int vv[4]) {
    const int   y1  = (y - 32) >> 6;
    const float ya  = (float)((y + 32) & 63) * (1.0f/64.0f);
    const int   y1i = y1 < 0 ? 0 : y1;
    const int   y2i = (y1 + 1) > 7 ? 7 : (y1 + 1);
    const uint8_t* lb  = lut + b * (64 * NBINS);
    const uint8_t* lr1 = lb + y1i * (8 * NBINS);
    const uint8_t* lr2 = lb + y2i * (8 * NBINS);
    const float iya = __fsub_rn(1.0f, ya);
    float res[4];
    #pragma unroll
    for (int j = 0; j < 4; ++j) {
        const int xx  = x + j;
        const int x1  = (xx - 32) >> 6;
        const float xa  = (float)((xx + 32) & 63) * (1.0f/64.0f);
        const int  x1i = x1 < 0 ? 0 : x1;
        const int  x2i = (x1 + 1) > 7 ? 7 : (x1 + 1);
        const int  v   = vv[j];
        const float r11 = (float)lr1[x1i * NBINS + v];
        const float r12 = (float)lr1[x2i * NBINS + v];
        const float r21 = (float)lr2[x1i * NBINS + v];
        const float r22 = (float)lr2[x2i * NBINS + v];
        const float ixa = __fsub_rn(1.0f, xa);
        const float top = __fadd_rn(__fmul_rn(r11, ixa), __fmul_rn(r12, xa));
        const float bot = __fadd_rn(__fmul_rn(r21, ixa), __fmul_rn(r22, xa));
        float r = __fadd_rn(__fmul_rn(top, iya), __fmul_rn(bot, ya));
        r = rintf(r);
        res[j] = fminf(fmaxf(r, 0.0f), 255.0f);
    }
    return make_float4(res[0], res[1], res[2], res[3]);
}

__global__ __launch_bounds__(256) void k_apply_recompute(const float* __restrict__ in,
                                                         const uint8_t* __restrict__ lut,
                                                         float* __restrict__ out) {
    const int nG = NPIX / 4;
    for (int g = blockIdx.x * blockDim.x + threadIdx.x; g < nG;
         g += gridDim.x * blockDim.x) {
        const int pix = g << 2;
        const int b   = pix >> 18;
        const int rem = pix & (IMG - 1);
        const int y   = rem >> 9;
        const int x   = rem & (WW - 1);
        const float4* p = (const float4*)(in + (size_t)pix * 3);
        float4 a0 = p[0], a1 = p[1], a2 = p[2];
        const int vv[4] = {gray_of(a0.x, a0.y, a0.z), gray_of(a0.w, a1.x, a1.y),
                           gray_of(a1.z, a1.w, a2.x), gray_of(a2.y, a2.z, a2.w)};
        float4 r = bilerp_group(lut, b, y, x, vv);
        float4* o = (float4*)(out + (size_t)pix * 3);
        o[0] = make_float4(r.x, r.x, r.x, r.y);
        o[1] = make_float4(r.y, r.y, r.z, r.z);
        o[2] = make_float4(r.z, r.w, r.w, r.w);
    }
}

extern "C" void kernel_launch(void* const* d_in, const int* in_sizes, int n_in,
                              void* d_out, int out_size, void* d_ws, size_t ws_size,
                              hipStream_t stream) {
    const float* in  = (const float*)d_in[0];
    float*       out = (float*)d_out;
    const size_t lut_bytes  = (size_t)NB * 64 * NBINS;   // 2 MB
    const size_t gray_bytes = (size_t)NPIX;              // 33.5 MB

    if (ws_size >= gray_bytes + lut_bytes) {
        uint8_t* gray = (uint8_t*)d_ws;
        uint8_t* lut  = (uint8_t*)d_ws + gray_bytes;
        k_hist_lut<true><<<NB * 64, 256, 0, stream>>>(in, gray, lut);
        k_apply2<<<NPIX / 1024, 256, 0, stream>>>(gray, lut, out);
    } else {
        uint8_t* lut = (uint8_t*)d_ws;
        k_hist_lut<false><<<NB * 64, 256, 0, stream>>>(in, nullptr, lut);
        k_apply_recompute<<<8192, 256, 0, stream>>>(in, lut, out);
    }
}